// Round 1
// baseline (217.842 us; speedup 1.0000x reference)
//
#include <hip/hip_runtime.h>
#include <math.h>

#define NPIX 16384      // 128*128
#define CHW  (64*16384)
#define ATT_SCALE 0.17677669529663687f  // 1/sqrt(32)

// ---------------- K0: fold weights, zero stats ----------------
__global__ void k0_fold(const float* __restrict__ w1a, const float* __restrict__ b1a,
                        const float* __restrict__ w1b, const float* __restrict__ b1b,
                        const float* __restrict__ w2,  const float* __restrict__ b2,
                        const float* __restrict__ wc,  const float* __restrict__ bc,
                        float* __restrict__ A1, float* __restrict__ b1f,
                        float* __restrict__ Wf, float* __restrict__ bf,
                        float* __restrict__ stats) {
  int tid = threadIdx.x;
  if (tid < 4) stats[tid] = 0.f;
  {
    // A1[o][c] = sum_k w1b[o][k] * w1a[k][c]   (o=tid>>6, c=tid&63)
    int o = tid >> 6, c = tid & 63;
    float s = 0.f;
    #pragma unroll
    for (int k = 0; k < 4; ++k) s += w1b[o*4+k] * w1a[k*64+c];
    A1[tid] = s;
  }
  if (tid < 4) {
    float s = b1b[tid];
    #pragma unroll
    for (int k = 0; k < 4; ++k) s += w1b[tid*4+k] * b1a[k];
    b1f[tid] = s;
  }
  {
    // Wf[o][c] = sum_k wc[o][k] * w2[k][c]   (o=tid>>2, c=tid&3)
    int o = tid >> 2, c = tid & 3;
    float s = 0.f;
    for (int k = 0; k < 64; ++k) s += wc[o*64+k] * w2[k*4+c];
    Wf[tid] = s;
  }
  if (tid < 64) {
    float s = bc[tid];
    for (int k = 0; k < 64; ++k) s += wc[tid*64+k] * b2[k];
    bf[tid] = s;
  }
}

// ---------------- K1: a = A1 @ x + b1f, accumulate sum/sumsq per batch ----------------
__global__ void k1_a_stats(const float* __restrict__ x, const float* __restrict__ A1,
                           const float* __restrict__ b1f, float* __restrict__ a,
                           float* __restrict__ stats) {
  __shared__ float sA[256];
  __shared__ float sb[4];
  __shared__ float red[128], red2[128];
  int tid = threadIdx.x;
  for (int k = tid; k < 256; k += 128) sA[k] = A1[k];
  if (tid < 4) sb[tid] = b1f[tid];
  __syncthreads();
  int pix = blockIdx.x * 128 + tid;
  int b = pix >> 14, rem = pix & 16383;
  const float* xb = x + b * CHW + rem;
  float acc0=0.f, acc1=0.f, acc2=0.f, acc3=0.f;
  #pragma unroll
  for (int c = 0; c < 64; ++c) {
    float xv = xb[c*16384];
    acc0 += sA[c]*xv; acc1 += sA[64+c]*xv; acc2 += sA[128+c]*xv; acc3 += sA[192+c]*xv;
  }
  acc0 += sb[0]; acc1 += sb[1]; acc2 += sb[2]; acc3 += sb[3];
  float* ab = a + b*4*16384 + rem;
  ab[0] = acc0; ab[16384] = acc1; ab[32768] = acc2; ab[49152] = acc3;
  float ls = acc0+acc1+acc2+acc3;
  float lq = acc0*acc0+acc1*acc1+acc2*acc2+acc3*acc3;
  red[tid] = ls; red2[tid] = lq; __syncthreads();
  for (int s = 64; s > 0; s >>= 1) {
    if (tid < s) { red[tid] += red[tid+s]; red2[tid] += red2[tid+s]; }
    __syncthreads();
  }
  if (tid == 0) { atomicAdd(&stats[b*2], red[0]); atomicAdd(&stats[b*2+1], red2[0]); }
}

// ---------------- K2: build tok and normalized qk per attention batch ----------------
// g = b*16 + u*4 + v  (u = channel of a, v = H-phase); t = i*32+j; token-chan k = W-phase
// tok[g][t][k] = ( (i*4+v>=64 ? a[b][u][i*4+v-64][j*4+k] : 0) - mu_b ) * rsig_b
__global__ void k2_tok_qk(const float* __restrict__ a, const float* __restrict__ stats,
                          const float* __restrict__ wqk,
                          float4* __restrict__ tok, float4* __restrict__ qk) {
  int g = blockIdx.x / 12;
  int t = (blockIdx.x % 12) * 128 + threadIdx.x;
  int b = g >> 4, u = (g >> 2) & 3, v = g & 3;
  int i = t >> 5, j = t & 31;
  float mu  = stats[b*2]   * (1.f/98304.f);
  float var = stats[b*2+1] * (1.f/98304.f) - mu*mu;
  float rsig = rsqrtf(var + 1e-5f);
  int Hp = i*4 + v;
  float4 tv;
  if (Hp >= 64) {
    const float* ap = a + (b*4+u)*16384 + (Hp-64)*128 + j*4;
    tv = *(const float4*)ap;
    tv.x = (tv.x - mu)*rsig; tv.y = (tv.y - mu)*rsig;
    tv.z = (tv.z - mu)*rsig; tv.w = (tv.w - mu)*rsig;
  } else {
    float z = -mu * rsig;
    tv = make_float4(z, z, z, z);
  }
  float q0 = tv.x*wqk[0] + tv.y*wqk[4] + tv.z*wqk[8]  + tv.w*wqk[12];
  float q1 = tv.x*wqk[1] + tv.y*wqk[5] + tv.z*wqk[9]  + tv.w*wqk[13];
  float q2 = tv.x*wqk[2] + tv.y*wqk[6] + tv.z*wqk[10] + tv.w*wqk[14];
  float q3 = tv.x*wqk[3] + tv.y*wqk[7] + tv.z*wqk[11] + tv.w*wqk[15];
  float nrm = sqrtf(q0*q0 + q1*q1 + q2*q2 + q3*q3);
  float inv = 1.f / (nrm + 1e-8f);
  int idx = g*1536 + t;
  tok[idx] = tv;
  qk[idx]  = make_float4(q0*inv, q1*inv, q2*inv, q3*inv);
}

// ---------------- K3: attention; keys 0..511 are identical -> 1 key with weight 512 ----
// only queries t<1024 are needed (crop removes i>=32). Output scattered to att layout.
__global__ void k3_attn(const float4* __restrict__ tok, const float4* __restrict__ qk,
                        float* __restrict__ att) {
  __shared__ float4 kq[1024];
  __shared__ float4 kt[1024];
  int g = blockIdx.x >> 3, qb = blockIdx.x & 7;
  int tid = threadIdx.x;
  const float4* qg = qk  + g*1536;
  const float4* tg = tok + g*1536;
  for (int m = tid; m < 1024; m += 128) { kq[m] = qg[512+m]; kt[m] = tg[512+m]; }
  __syncthreads();
  int t = qb*128 + tid;            // [0,1024)
  float4 q = qg[t];
  float4 qk0 = qg[0];
  float4 tok0 = tg[0];
  float e0 = __expf((q.x*qk0.x + q.y*qk0.y + q.z*qk0.z + q.w*qk0.w + 1.f) * ATT_SCALE);
  float den = 512.f * e0;
  float ox = den*tok0.x, oy = den*tok0.y, oz = den*tok0.z, ow = den*tok0.w;
  #pragma unroll 4
  for (int m = 0; m < 1024; ++m) {
    float4 km = kq[m];
    float s = q.x*km.x + q.y*km.y + q.z*km.z + q.w*km.w;
    float e = __expf((s + 1.f) * ATT_SCALE);
    float4 tm = kt[m];
    den += e;
    ox += e*tm.x; oy += e*tm.y; oz += e*tm.z; ow += e*tm.w;
  }
  float inv = 1.f / den;
  int b = g >> 4, u = (g >> 2) & 3, v = g & 3;
  int i = t >> 5, j = t & 31;
  float* ap = att + b*4*16384 + (i*4+u)*128 + (j*4+v);
  ap[0]     = ox*inv;
  ap[16384] = oy*inv;
  ap[32768] = oz*inv;
  ap[49152] = ow*inv;
}

// ---------------- K4: y = x + Wf@att + bf (write to d_out) ; h1 = relu(wf1@y+bf1) ------
__global__ void k4_y_h1(const float* __restrict__ x, const float* __restrict__ att,
                        const float* __restrict__ Wf, const float* __restrict__ bf,
                        const float* __restrict__ wf1, const float* __restrict__ bf1,
                        float* __restrict__ yout, float* __restrict__ h1) {
  __shared__ float sW[256], sb[64], sw1[1024], sb1[16];
  int tid = threadIdx.x;
  for (int k = tid; k < 256; k += 128) sW[k] = Wf[k];
  for (int k = tid; k < 1024; k += 128) sw1[k] = wf1[k];
  if (tid < 64) sb[tid] = bf[tid];
  if (tid < 16) sb1[tid] = bf1[tid];
  __syncthreads();
  int pix = blockIdx.x*128 + tid;
  int b = pix >> 14, rem = pix & 16383;
  const float* ap = att + b*4*16384 + rem;
  float a0 = ap[0], a1 = ap[16384], a2 = ap[32768], a3 = ap[49152];
  const float* xp = x + b*CHW + rem;
  float* yp = yout + b*CHW + rem;
  float yv[64];
  #pragma unroll
  for (int o = 0; o < 64; ++o) {
    float v = xp[o*16384] + sW[o*4]*a0 + sW[o*4+1]*a1 + sW[o*4+2]*a2 + sW[o*4+3]*a3 + sb[o];
    yv[o] = v;
    yp[o*16384] = v;
  }
  float* hp = h1 + b*16*16384 + rem;
  #pragma unroll
  for (int o2 = 0; o2 < 16; ++o2) {
    float s = sb1[o2];
    #pragma unroll
    for (int c = 0; c < 64; ++c) s += sw1[o2*64+c] * yv[c];
    hp[o2*16384] = fmaxf(s, 0.f);
  }
}

// ---------------- K6: out = y + wf3 @ relu(dilated_conv(h1)+bf2) + bf3 ----------------
// taps: rows {h-5,h-3,h-1}, cols {w-2,w,w+2}, zero-padded
__global__ void k6_ff_out(const float* __restrict__ h1,
                          const float* __restrict__ wf2, const float* __restrict__ bf2,
                          const float* __restrict__ wf3, const float* __restrict__ bf3,
                          float* yo /* d_out: read y, write final */) {
  __shared__ float s2[2304], s3[1024], sb2[16], sb3[64];
  int tid = threadIdx.x;
  for (int k = tid; k < 2304; k += 128) s2[k] = wf2[k];
  for (int k = tid; k < 1024; k += 128) s3[k] = wf3[k];
  if (tid < 16) sb2[tid] = bf2[tid];
  if (tid < 64) sb3[tid] = bf3[tid];
  __syncthreads();
  int pix = blockIdx.x*128 + tid;
  int b = pix >> 14, rem = pix & 16383;
  int h = rem >> 7, w = rem & 127;
  float acc[16];
  #pragma unroll
  for (int o2 = 0; o2 < 16; ++o2) acc[o2] = sb2[o2];
  const float* hb = h1 + b*16*16384;
  for (int c = 0; c < 16; ++c) {
    const float* hc = hb + c*16384;
    #pragma unroll
    for (int ti = 0; ti < 3; ++ti) {
      int row = h + 2*ti - 5;            // always < 128
      bool rok = (row >= 0);
      const float* hr = hc + row*128;
      #pragma unroll
      for (int tj = 0; tj < 3; ++tj) {
        int col = w + 2*tj - 2;
        float val = (rok && col >= 0 && col < 128) ? hr[col] : 0.f;
        #pragma unroll
        for (int o2 = 0; o2 < 16; ++o2)
          acc[o2] += s2[((o2*16+c)*3+ti)*3+tj] * val;
      }
    }
  }
  float h2[16];
  #pragma unroll
  for (int o2 = 0; o2 < 16; ++o2) h2[o2] = fmaxf(acc[o2], 0.f);
  float* yp = yo + b*CHW + rem;
  #pragma unroll
  for (int o = 0; o < 64; ++o) {
    float s = sb3[o] + yp[o*16384];
    #pragma unroll
    for (int o2 = 0; o2 < 16; ++o2) s += s3[o*16+o2] * h2[o2];
    yp[o*16384] = s;
  }
}

extern "C" void kernel_launch(void* const* d_in, const int* in_sizes, int n_in,
                              void* d_out, int out_size, void* d_ws, size_t ws_size,
                              hipStream_t stream) {
  (void)in_sizes; (void)n_in; (void)out_size; (void)ws_size;
  const float* x   = (const float*)d_in[0];
  const float* w1a = (const float*)d_in[1];
  const float* b1a = (const float*)d_in[2];
  const float* w1b = (const float*)d_in[3];
  const float* b1b = (const float*)d_in[4];
  const float* wqk = (const float*)d_in[5];
  const float* w2  = (const float*)d_in[6];
  const float* b2  = (const float*)d_in[7];
  const float* wc  = (const float*)d_in[8];
  const float* bc  = (const float*)d_in[9];
  const float* wf1 = (const float*)d_in[10];
  const float* bf1 = (const float*)d_in[11];
  const float* wf2 = (const float*)d_in[12];
  const float* bf2 = (const float*)d_in[13];
  const float* wf3 = (const float*)d_in[14];
  const float* bf3 = (const float*)d_in[15];

  float* ws   = (float*)d_ws;
  float* a_   = ws;                       // 131072
  float* stats= ws + 131072;              // 4
  float* A1   = ws + 131088;              // 256
  float* b1f  = ws + 131344;              // 16
  float* Wf   = ws + 131360;              // 256
  float* bf   = ws + 131616;              // 64
  float4* tok = (float4*)(ws + 131680);   // 196608 floats
  float4* qkb = (float4*)(ws + 328288);   // 196608 floats
  float* att  = ws + 524896;              // 131072
  float* h1   = ws + 655968;              // 524288
  float* y    = (float*)d_out;            // stage y in d_out, overwritten by K6

  k0_fold<<<1, 256, 0, stream>>>(w1a, b1a, w1b, b1b, w2, b2, wc, bc, A1, b1f, Wf, bf, stats);
  k1_a_stats<<<256, 128, 0, stream>>>(x, A1, b1f, a_, stats);
  k2_tok_qk<<<384, 128, 0, stream>>>(a_, stats, wqk, tok, qkb);
  k3_attn<<<256, 128, 0, stream>>>(tok, qkb, att);
  k4_y_h1<<<256, 128, 0, stream>>>(x, att, Wf, bf, wf1, bf1, y, h1);
  k6_ff_out<<<256, 128, 0, stream>>>(h1, wf2, bf2, wf3, bf3, y);
}

// Round 2
// 156.241 us; speedup vs baseline: 1.3943x; 1.3943x over previous
//
#include <hip/hip_runtime.h>
#include <math.h>

#define CHW  (64*16384)
#define ATT_SCALE 0.17677669529663687f  // 1/sqrt(32)

// ================= K1: a = (w1b@w1a)@x + b, per-block stats partials =================
// block: 32 pixel-quads x 8 channel-groups (input-channel split). 256 blocks.
__global__ __launch_bounds__(256) void k1_a_stats(
    const float* __restrict__ x, const float* __restrict__ w1a,
    const float* __restrict__ b1a, const float* __restrict__ w1b,
    const float* __restrict__ b1b, float* __restrict__ a,
    float* __restrict__ statsbuf) {
  __shared__ float sA[256];          // A1[o*64+c] = (w1b@w1a)
  __shared__ float sb1[4];
  __shared__ float4 part[8][32][4];  // [cg][quad][o]
  __shared__ float rs[128], rq[128];
  int tid = threadIdx.x;
  {
    int o = tid >> 6, c = tid & 63;
    float s = 0.f;
    #pragma unroll
    for (int k = 0; k < 4; ++k) s += w1b[o*4+k] * w1a[k*64+c];
    sA[tid] = s;
  }
  if (tid < 4) {
    float s = b1b[tid];
    #pragma unroll
    for (int k = 0; k < 4; ++k) s += w1b[tid*4+k] * b1a[k];
    sb1[tid] = s;
  }
  __syncthreads();
  int quad = tid & 31, cg = tid >> 5;
  int gq = blockIdx.x * 32 + quad;
  int bb = gq >> 12;
  int px0 = (gq & 4095) * 4;
  const float* xp = x + bb*CHW + (cg*8)*16384 + px0;
  float4 acc[4];
  #pragma unroll
  for (int o = 0; o < 4; ++o) acc[o] = make_float4(0.f,0.f,0.f,0.f);
  #pragma unroll
  for (int cc = 0; cc < 8; ++cc) {
    float4 xv = *(const float4*)(xp + cc*16384);
    int c = cg*8 + cc;
    #pragma unroll
    for (int o = 0; o < 4; ++o) {
      float w = sA[o*64+c];
      acc[o].x += w*xv.x; acc[o].y += w*xv.y; acc[o].z += w*xv.z; acc[o].w += w*xv.w;
    }
  }
  #pragma unroll
  for (int o = 0; o < 4; ++o) part[cg][quad][o] = acc[o];
  __syncthreads();
  float ls = 0.f, lq = 0.f;
  if (tid < 128) {
    int q2 = tid & 31, o = tid >> 5;
    float4 s = part[0][q2][o];
    #pragma unroll
    for (int g2 = 1; g2 < 8; ++g2) {
      float4 p = part[g2][q2][o];
      s.x += p.x; s.y += p.y; s.z += p.z; s.w += p.w;
    }
    float bv = sb1[o];
    s.x += bv; s.y += bv; s.z += bv; s.w += bv;
    int gq2 = blockIdx.x*32 + q2;
    int b2 = gq2 >> 12; int p0 = (gq2 & 4095)*4;
    *(float4*)(a + b2*4*16384 + o*16384 + p0) = s;
    ls = s.x+s.y+s.z+s.w;
    lq = s.x*s.x+s.y*s.y+s.z*s.z+s.w*s.w;
    rs[tid] = ls; rq[tid] = lq;
  }
  __syncthreads();
  for (int s2 = 64; s2; s2 >>= 1) {
    if (tid < s2) { rs[tid] += rs[tid+s2]; rq[tid] += rq[tid+s2]; }
    __syncthreads();
  }
  if (tid == 0) { statsbuf[blockIdx.x*2] = rs[0]; statsbuf[blockIdx.x*2+1] = rq[0]; }
}

// ================= K2: tok + normalized qk (reduces stats partials) =================
__global__ __launch_bounds__(256) void k2_tok_qk(
    const float* __restrict__ a, const float* __restrict__ statsbuf,
    const float* __restrict__ wqk, float4* __restrict__ tok,
    float4* __restrict__ qko) {
  __shared__ float rs[128], rq[128];
  int tid = threadIdx.x;
  int g = blockIdx.x / 6;
  int t = (blockIdx.x % 6) * 256 + tid;
  int b = g >> 4, u = (g >> 2) & 3, v = g & 3;
  if (tid < 128) {
    rs[tid] = statsbuf[(b*128+tid)*2];
    rq[tid] = statsbuf[(b*128+tid)*2+1];
  }
  __syncthreads();
  for (int s2 = 64; s2; s2 >>= 1) {
    if (tid < s2) { rs[tid] += rs[tid+s2]; rq[tid] += rq[tid+s2]; }
    __syncthreads();
  }
  float mu  = rs[0] * (1.f/98304.f);
  float var = rq[0] * (1.f/98304.f) - mu*mu;
  float rsig = rsqrtf(var + 1e-5f);
  int i = t >> 5, j = t & 31;
  int Hp = i*4 + v;
  float4 tv;
  if (Hp >= 64) {
    tv = *(const float4*)(a + (b*4+u)*16384 + (Hp-64)*128 + j*4);
    tv.x = (tv.x-mu)*rsig; tv.y = (tv.y-mu)*rsig;
    tv.z = (tv.z-mu)*rsig; tv.w = (tv.w-mu)*rsig;
  } else {
    float z = -mu*rsig;
    tv = make_float4(z,z,z,z);
  }
  float q0 = tv.x*wqk[0] + tv.y*wqk[4] + tv.z*wqk[8]  + tv.w*wqk[12];
  float q1 = tv.x*wqk[1] + tv.y*wqk[5] + tv.z*wqk[9]  + tv.w*wqk[13];
  float q2 = tv.x*wqk[2] + tv.y*wqk[6] + tv.z*wqk[10] + tv.w*wqk[14];
  float q3 = tv.x*wqk[3] + tv.y*wqk[7] + tv.z*wqk[11] + tv.w*wqk[15];
  float nrm = sqrtf(q0*q0 + q1*q1 + q2*q2 + q3*q3);
  float inv = 1.f / (nrm + 1e-8f);
  int idx = g*1536 + t;
  tok[idx] = tv;
  qko[idx] = make_float4(q0*inv, q1*inv, q2*inv, q3*inv);
}

// ================= K3: attention. 4 queries/thread, 8-way key split ==================
// exp((s+1)*c) = e^c * poly(s*c); the e^c factor cancels in softmax -> poly only.
__device__ __forceinline__ float poly_exp(float d) {
  // exp(d), |d| <= 0.1768 ; 4th order Taylor, rel err ~1.4e-6
  return 1.f + d*(1.f + d*(0.5f + d*(0.16666667f + d*0.04166667f)));
}
__global__ __launch_bounds__(256) void k3_attn(
    const float4* __restrict__ tok, const float4* __restrict__ qk,
    float* __restrict__ att) {
  __shared__ float4 kq[1024];
  __shared__ float4 kt[1024];
  __shared__ float red[128][8][5];
  int tid = threadIdx.x;
  int g = blockIdx.x >> 3, qb = blockIdx.x & 7;
  const float4* qg = qk  + g*1536;
  const float4* tg = tok + g*1536;
  for (int m = tid; m < 1024; m += 256) { kq[m] = qg[512+m]; kt[m] = tg[512+m]; }
  __syncthreads();
  int s = tid >> 5, qi = tid & 31;
  int t0 = qb*128 + qi*4;
  float4 q[4];
  #pragma unroll
  for (int j = 0; j < 4; ++j) {
    float4 v = qg[t0+j];
    q[j] = make_float4(v.x*ATT_SCALE, v.y*ATT_SCALE, v.z*ATT_SCALE, v.w*ATT_SCALE);
  }
  float den[4] = {0.f,0.f,0.f,0.f};
  float4 ov[4];
  #pragma unroll
  for (int j = 0; j < 4; ++j) ov[j] = make_float4(0.f,0.f,0.f,0.f);
  if (s == 0) {  // the 512 identical zero-pad keys, folded into one weighted term
    float4 k0 = qg[0]; float4 tv0 = tg[0];
    #pragma unroll
    for (int j = 0; j < 4; ++j) {
      float d = q[j].x*k0.x + q[j].y*k0.y + q[j].z*k0.z + q[j].w*k0.w;
      float e = 512.f * poly_exp(d);
      den[j] += e;
      ov[j].x += e*tv0.x; ov[j].y += e*tv0.y; ov[j].z += e*tv0.z; ov[j].w += e*tv0.w;
    }
  }
  int m0 = s * 128;
  #pragma unroll 2
  for (int m = m0; m < m0 + 128; ++m) {
    float4 kk = kq[m];
    float4 tv = kt[m];
    #pragma unroll
    for (int j = 0; j < 4; ++j) {
      float d = q[j].x*kk.x + q[j].y*kk.y + q[j].z*kk.z + q[j].w*kk.w;
      float e = poly_exp(d);
      den[j] += e;
      ov[j].x += e*tv.x; ov[j].y += e*tv.y; ov[j].z += e*tv.z; ov[j].w += e*tv.w;
    }
  }
  #pragma unroll
  for (int j = 0; j < 4; ++j) {
    red[qi*4+j][s][0] = den[j];
    red[qi*4+j][s][1] = ov[j].x; red[qi*4+j][s][2] = ov[j].y;
    red[qi*4+j][s][3] = ov[j].z; red[qi*4+j][s][4] = ov[j].w;
  }
  __syncthreads();
  if (tid < 128) {
    float dsum=0.f, ox=0.f, oy=0.f, oz=0.f, ow=0.f;
    #pragma unroll
    for (int ss = 0; ss < 8; ++ss) {
      dsum += red[tid][ss][0];
      ox += red[tid][ss][1]; oy += red[tid][ss][2];
      oz += red[tid][ss][3]; ow += red[tid][ss][4];
    }
    float inv = 1.f / dsum;
    int t = qb*128 + tid;
    int b = g >> 4, u = (g >> 2) & 3, v = g & 3;
    int i = t >> 5, j = t & 31;
    float* ap = att + b*4*16384 + (i*4+u)*128 + (j*4+v);
    ap[0]     = ox*inv;
    ap[16384] = oy*inv;
    ap[32768] = oz*inv;
    ap[49152] = ow*inv;
  }
}

// ================= K4: y = x + (wc@w2)@att + bias (to d_out); h1 = relu(wf1@y) =======
// block: 32 quads x 8 output-channel-groups. y staged in LDS for the h1 phase.
__global__ __launch_bounds__(256) void k4_y_h1(
    const float* __restrict__ x, const float* __restrict__ att,
    const float* __restrict__ w2p, const float* __restrict__ b2p,
    const float* __restrict__ wcp, const float* __restrict__ bcp,
    const float* __restrict__ wf1, const float* __restrict__ bf1,
    float* __restrict__ yout, float* __restrict__ h1) {
  __shared__ float sWf[64][4];
  __shared__ float sbf[64];
  __shared__ float sw1[1024];
  __shared__ float sb1[16];
  __shared__ float4 satt[4][32];
  __shared__ float4 ylds[64][32];
  int tid = threadIdx.x;
  {
    int o = tid >> 2, k = tid & 3;
    float s = 0.f;
    for (int c = 0; c < 64; ++c) s += wcp[o*64+c] * w2p[c*4+k];
    sWf[o][k] = s;
  }
  if (tid < 64) {
    float s = bcp[tid];
    for (int c = 0; c < 64; ++c) s += wcp[tid*64+c] * b2p[c];
    sbf[tid] = s;
  }
  for (int i = tid; i < 1024; i += 256) sw1[i] = wf1[i];
  if (tid < 16) sb1[tid] = bf1[tid];
  int quad = tid & 31, og = tid >> 5;
  int gq = blockIdx.x*32 + quad;
  int bb = gq >> 12; int px0 = (gq & 4095)*4;
  if (tid < 128) {
    int k = tid >> 5, q2 = tid & 31;
    int gq2 = blockIdx.x*32 + q2;
    int b2i = gq2 >> 12; int p0 = (gq2 & 4095)*4;
    satt[k][q2] = *(const float4*)(att + b2i*4*16384 + k*16384 + p0);
  }
  __syncthreads();
  float4 a0 = satt[0][quad], a1 = satt[1][quad], a2 = satt[2][quad], a3 = satt[3][quad];
  const float* xp = x + bb*CHW + px0;
  float* yp = yout + bb*CHW + px0;
  #pragma unroll
  for (int cc = 0; cc < 8; ++cc) {
    int c = og*8 + cc;
    float4 xv = *(const float4*)(xp + c*16384);
    float w0 = sWf[c][0], w1 = sWf[c][1], w2v = sWf[c][2], w3 = sWf[c][3];
    float bv = sbf[c];
    float4 yv;
    yv.x = xv.x + w0*a0.x + w1*a1.x + w2v*a2.x + w3*a3.x + bv;
    yv.y = xv.y + w0*a0.y + w1*a1.y + w2v*a2.y + w3*a3.y + bv;
    yv.z = xv.z + w0*a0.z + w1*a1.z + w2v*a2.z + w3*a3.z + bv;
    yv.w = xv.w + w0*a0.w + w1*a1.w + w2v*a2.w + w3*a3.w + bv;
    *(float4*)(yp + c*16384) = yv;
    ylds[c][quad] = yv;
  }
  __syncthreads();
  int o2a = og*2, o2b = og*2+1;
  float4 acc0 = make_float4(sb1[o2a], sb1[o2a], sb1[o2a], sb1[o2a]);
  float4 acc1 = make_float4(sb1[o2b], sb1[o2b], sb1[o2b], sb1[o2b]);
  #pragma unroll 8
  for (int c = 0; c < 64; ++c) {
    float4 yv = ylds[c][quad];
    float wa = sw1[o2a*64+c], wb = sw1[o2b*64+c];
    acc0.x += wa*yv.x; acc0.y += wa*yv.y; acc0.z += wa*yv.z; acc0.w += wa*yv.w;
    acc1.x += wb*yv.x; acc1.y += wb*yv.y; acc1.z += wb*yv.z; acc1.w += wb*yv.w;
  }
  acc0.x = fmaxf(acc0.x,0.f); acc0.y = fmaxf(acc0.y,0.f);
  acc0.z = fmaxf(acc0.z,0.f); acc0.w = fmaxf(acc0.w,0.f);
  acc1.x = fmaxf(acc1.x,0.f); acc1.y = fmaxf(acc1.y,0.f);
  acc1.z = fmaxf(acc1.z,0.f); acc1.w = fmaxf(acc1.w,0.f);
  float* hp = h1 + bb*16*16384 + px0;
  *(float4*)(hp + o2a*16384) = acc0;
  *(float4*)(hp + o2b*16384) = acc1;
}

// ================= K6: out = y + wf3@relu(dilconv(h1)+bf2) + bf3 =====================
// block = one output row (128 px) x 2 wave-uniform o2-groups; tap rows staged in LDS.
__global__ __launch_bounds__(256) void k6_ff_out(
    const float* __restrict__ h1, const float* __restrict__ wf2,
    const float* __restrict__ bf2, const float* __restrict__ wf3,
    const float* __restrict__ bf3, float* yo) {
  __shared__ float sbuf[16][3][136];   // data at col+4; 4-col zero pads both sides
  __shared__ float h2buf[128][21];     // pad 21: stride coprime with 32 banks
  int tid = threadIdx.x;
  int bb = blockIdx.x >> 7, h = blockIdx.x & 127;
  for (int idx = tid; idx < 16*3*136; idx += 256) {
    int c = idx / (3*136);
    int r = (idx / 136) % 3;
    int col = idx % 136;
    int row = h - 5 + 2*r;
    int w = col - 4;
    float v = 0.f;
    if (row >= 0 && w >= 0 && w < 128)
      v = h1[bb*16*16384 + c*16384 + row*128 + w];
    sbuf[c][r][col] = v;
  }
  __syncthreads();
  int w = tid & 127;
  int g = __builtin_amdgcn_readfirstlane(tid >> 7);   // wave-uniform o2-group
  float acc[8];
  #pragma unroll
  for (int o = 0; o < 8; ++o) acc[o] = bf2[g*8+o];
  #pragma unroll 4
  for (int c = 0; c < 16; ++c) {
    #pragma unroll
    for (int r = 0; r < 3; ++r) {
      float tm2 = sbuf[c][r][w+2];
      float t00 = sbuf[c][r][w+4];
      float tp2 = sbuf[c][r][w+6];
      #pragma unroll
      for (int o = 0; o < 8; ++o) {
        const float* wp = wf2 + (((g*8+o)*16 + c)*3 + r)*3;
        acc[o] += wp[0]*tm2 + wp[1]*t00 + wp[2]*tp2;
      }
    }
  }
  #pragma unroll
  for (int o = 0; o < 8; ++o) h2buf[w][g*8+o] = fmaxf(acc[o], 0.f);
  __syncthreads();
  float hv[16];
  #pragma unroll
  for (int k = 0; k < 16; ++k) hv[k] = h2buf[w][k];
  float* ybase = yo + bb*CHW + h*128 + w;
  #pragma unroll 4
  for (int oc = 0; oc < 32; ++oc) {
    int o = g*32 + oc;
    float sv = bf3[o] + ybase[o*16384];
    #pragma unroll
    for (int k = 0; k < 16; ++k) sv += wf3[o*16+k]*hv[k];
    ybase[o*16384] = sv;
  }
}

extern "C" void kernel_launch(void* const* d_in, const int* in_sizes, int n_in,
                              void* d_out, int out_size, void* d_ws, size_t ws_size,
                              hipStream_t stream) {
  (void)in_sizes; (void)n_in; (void)out_size; (void)ws_size;
  const float* x   = (const float*)d_in[0];
  const float* w1a = (const float*)d_in[1];
  const float* b1a = (const float*)d_in[2];
  const float* w1b = (const float*)d_in[3];
  const float* b1b = (const float*)d_in[4];
  const float* wqk = (const float*)d_in[5];
  const float* w2  = (const float*)d_in[6];
  const float* b2  = (const float*)d_in[7];
  const float* wc  = (const float*)d_in[8];
  const float* bc  = (const float*)d_in[9];
  const float* wf1 = (const float*)d_in[10];
  const float* bf1 = (const float*)d_in[11];
  const float* wf2 = (const float*)d_in[12];
  const float* bf2 = (const float*)d_in[13];
  const float* wf3 = (const float*)d_in[14];
  const float* bf3 = (const float*)d_in[15];

  float* ws = (float*)d_ws;
  float*  a_    = ws;                          // 131072 floats
  float*  stats = ws + 131072;                 // 512
  float4* tok   = (float4*)(ws + 131584);      // 196608 floats
  float4* qkb   = (float4*)(ws + 328192);      // 196608 floats
  float*  att   = ws + 524800;                 // 131072
  float*  h1    = ws + 655872;                 // 524288
  float*  y     = (float*)d_out;               // y staged in d_out; K6 finalizes in place

  k1_a_stats<<<256, 256, 0, stream>>>(x, w1a, b1a, w1b, b1b, a_, stats);
  k2_tok_qk <<<192, 256, 0, stream>>>(a_, stats, wqk, tok, qkb);
  k3_attn   <<<256, 256, 0, stream>>>(tok, qkb, att);
  k4_y_h1   <<<256, 256, 0, stream>>>(x, att, w2, b2, wc, bc, wf1, bf1, y, h1);
  k6_ff_out <<<256, 256, 0, stream>>>(h1, wf2, bf2, wf3, bf3, y);
}

// Round 3
// 134.149 us; speedup vs baseline: 1.6239x; 1.1647x over previous
//
#include <hip/hip_runtime.h>
#include <math.h>

#define CHW  (64*16384)
#define ATT_SCALE 0.17677669529663687f  // 1/sqrt(32)

// ================= K1: a = (w1b@w1a)@x + b, per-block stats partials =================
// 512 blocks x 256 threads: block = 16 pixel-quads x 16 channel-groups (4 ch each).
__global__ __launch_bounds__(256) void k1_a_stats(
    const float* __restrict__ x, const float* __restrict__ w1a,
    const float* __restrict__ b1a, const float* __restrict__ w1b,
    const float* __restrict__ b1b, float* __restrict__ a,
    float* __restrict__ statsbuf) {
  __shared__ float sA[256];          // A1 = w1b@w1a
  __shared__ float sb1[4];
  __shared__ float pc[4][4][256];    // [comp][o][cg*16+quad]  lane-stride-1
  __shared__ float rs[64], rq[64];
  int tid = threadIdx.x;
  {
    int o = tid >> 6, c = tid & 63;
    float s = 0.f;
    #pragma unroll
    for (int k = 0; k < 4; ++k) s += w1b[o*4+k] * w1a[k*64+c];
    sA[tid] = s;
  }
  if (tid < 4) {
    float s = b1b[tid];
    #pragma unroll
    for (int k = 0; k < 4; ++k) s += w1b[tid*4+k] * b1a[k];
    sb1[tid] = s;
  }
  __syncthreads();
  int quad = tid & 15, cg = tid >> 4;
  int gq = blockIdx.x * 16 + quad;       // [0, 8192)
  int bb = gq >> 12;
  int px0 = (gq & 4095) * 4;
  const float* xp = x + bb*CHW + (cg*4)*16384 + px0;
  float4 acc[4];
  #pragma unroll
  for (int o = 0; o < 4; ++o) acc[o] = make_float4(0.f,0.f,0.f,0.f);
  #pragma unroll
  for (int cc = 0; cc < 4; ++cc) {
    float4 xv = *(const float4*)(xp + cc*16384);
    int c = cg*4 + cc;
    #pragma unroll
    for (int o = 0; o < 4; ++o) {
      float w = sA[o*64+c];
      acc[o].x += w*xv.x; acc[o].y += w*xv.y; acc[o].z += w*xv.z; acc[o].w += w*xv.w;
    }
  }
  #pragma unroll
  for (int o = 0; o < 4; ++o) {
    pc[0][o][tid] = acc[o].x; pc[1][o][tid] = acc[o].y;
    pc[2][o][tid] = acc[o].z; pc[3][o][tid] = acc[o].w;
  }
  __syncthreads();
  if (tid < 64) {
    int q2 = tid & 15, o = tid >> 4;
    float sx=0.f, sy=0.f, sz=0.f, sw=0.f;
    #pragma unroll
    for (int g2 = 0; g2 < 16; ++g2) {
      int idx = g2*16 + q2;
      sx += pc[0][o][idx]; sy += pc[1][o][idx];
      sz += pc[2][o][idx]; sw += pc[3][o][idx];
    }
    float bv = sb1[o];
    sx += bv; sy += bv; sz += bv; sw += bv;
    int gq2 = blockIdx.x*16 + q2;
    int b2 = gq2 >> 12; int p0 = (gq2 & 4095)*4;
    *(float4*)(a + b2*4*16384 + o*16384 + p0) = make_float4(sx,sy,sz,sw);
    rs[tid] = sx+sy+sz+sw;
    rq[tid] = sx*sx+sy*sy+sz*sz+sw*sw;
  }
  __syncthreads();
  for (int s2 = 32; s2; s2 >>= 1) {
    if (tid < s2) { rs[tid] += rs[tid+s2]; rq[tid] += rq[tid+s2]; }
    __syncthreads();
  }
  if (tid == 0) { statsbuf[blockIdx.x*2] = rs[0]; statsbuf[blockIdx.x*2+1] = rq[0]; }
}

// ================= K2: tok + normalized qk (reduces 256 stats partials/batch) ========
__global__ __launch_bounds__(256) void k2_tok_qk(
    const float* __restrict__ a, const float* __restrict__ statsbuf,
    const float* __restrict__ wqk, float4* __restrict__ tok,
    float4* __restrict__ qko) {
  __shared__ float rs[256], rq[256];
  int tid = threadIdx.x;
  int g = blockIdx.x / 6;
  int t = (blockIdx.x % 6) * 256 + tid;
  int b = g >> 4, u = (g >> 2) & 3, v = g & 3;
  rs[tid] = statsbuf[(b*256+tid)*2];
  rq[tid] = statsbuf[(b*256+tid)*2+1];
  __syncthreads();
  for (int s2 = 128; s2; s2 >>= 1) {
    if (tid < s2) { rs[tid] += rs[tid+s2]; rq[tid] += rq[tid+s2]; }
    __syncthreads();
  }
  float mu  = rs[0] * (1.f/98304.f);
  float var = rq[0] * (1.f/98304.f) - mu*mu;
  float rsig = rsqrtf(var + 1e-5f);
  int i = t >> 5, j = t & 31;
  int Hp = i*4 + v;
  float4 tv;
  if (Hp >= 64) {
    tv = *(const float4*)(a + (b*4+u)*16384 + (Hp-64)*128 + j*4);
    tv.x = (tv.x-mu)*rsig; tv.y = (tv.y-mu)*rsig;
    tv.z = (tv.z-mu)*rsig; tv.w = (tv.w-mu)*rsig;
  } else {
    float z = -mu*rsig;
    tv = make_float4(z,z,z,z);
  }
  float q0 = tv.x*wqk[0] + tv.y*wqk[4] + tv.z*wqk[8]  + tv.w*wqk[12];
  float q1 = tv.x*wqk[1] + tv.y*wqk[5] + tv.z*wqk[9]  + tv.w*wqk[13];
  float q2 = tv.x*wqk[2] + tv.y*wqk[6] + tv.z*wqk[10] + tv.w*wqk[14];
  float q3 = tv.x*wqk[3] + tv.y*wqk[7] + tv.z*wqk[11] + tv.w*wqk[15];
  float nrm = sqrtf(q0*q0 + q1*q1 + q2*q2 + q3*q3);
  float inv = 1.f / (nrm + 1e-8f);
  int idx = g*1536 + t;
  tok[idx] = tv;
  qko[idx] = make_float4(q0*inv, q1*inv, q2*inv, q3*inv);
}

// ================= K3: attention. 512 thr: 32 q-slots x 16-way key split =============
__device__ __forceinline__ float poly_exp(float d) {
  // exp(d), |d| <= 0.1768 ; deg-4 Taylor, rel err ~1.4e-6; e^c factor cancels in softmax
  return 1.f + d*(1.f + d*(0.5f + d*(0.16666667f + d*0.04166667f)));
}
__global__ __launch_bounds__(512) void k3_attn(
    const float4* __restrict__ tok, const float4* __restrict__ qk,
    float* __restrict__ att) {
  __shared__ float4 kq[1024];
  __shared__ float4 kt[1024];
  __shared__ float red[16][5][128];   // [s][comp][j*32+qi]  lane-stride-1 both ways
  int tid = threadIdx.x;
  int g = blockIdx.x >> 3, qb = blockIdx.x & 7;
  const float4* qg = qk  + g*1536;
  const float4* tg = tok + g*1536;
  for (int m = tid; m < 1024; m += 512) { kq[m] = qg[512+m]; kt[m] = tg[512+m]; }
  __syncthreads();
  int qi = tid & 31, s = tid >> 5;      // s in [0,16)
  int t0 = qb*128 + qi*4;
  float4 q[4];
  #pragma unroll
  for (int j = 0; j < 4; ++j) {
    float4 v = qg[t0+j];
    q[j] = make_float4(v.x*ATT_SCALE, v.y*ATT_SCALE, v.z*ATT_SCALE, v.w*ATT_SCALE);
  }
  float den[4] = {0.f,0.f,0.f,0.f};
  float4 ov[4];
  #pragma unroll
  for (int j = 0; j < 4; ++j) ov[j] = make_float4(0.f,0.f,0.f,0.f);
  if (s == 0) {  // 512 identical zero-pad keys folded into one weighted term
    float4 k0 = qg[0]; float4 tv0 = tg[0];
    #pragma unroll
    for (int j = 0; j < 4; ++j) {
      float d = q[j].x*k0.x + q[j].y*k0.y + q[j].z*k0.z + q[j].w*k0.w;
      float e = 512.f * poly_exp(d);
      den[j] += e;
      ov[j].x += e*tv0.x; ov[j].y += e*tv0.y; ov[j].z += e*tv0.z; ov[j].w += e*tv0.w;
    }
  }
  int m0 = s * 64;
  #pragma unroll 2
  for (int m = m0; m < m0 + 64; ++m) {
    float4 kk = kq[m];
    float4 tv = kt[m];
    #pragma unroll
    for (int j = 0; j < 4; ++j) {
      float d = q[j].x*kk.x + q[j].y*kk.y + q[j].z*kk.z + q[j].w*kk.w;
      float e = poly_exp(d);
      den[j] += e;
      ov[j].x += e*tv.x; ov[j].y += e*tv.y; ov[j].z += e*tv.z; ov[j].w += e*tv.w;
    }
  }
  #pragma unroll
  for (int j = 0; j < 4; ++j) {
    int key = j*32 + qi;
    red[s][0][key] = den[j];
    red[s][1][key] = ov[j].x; red[s][2][key] = ov[j].y;
    red[s][3][key] = ov[j].z; red[s][4][key] = ov[j].w;
  }
  __syncthreads();
  if (tid < 128) {
    int qi_r = tid & 31, j_r = tid >> 5;     // key' = j_r*32+qi_r = tid
    float dsum=0.f, ox=0.f, oy=0.f, oz=0.f, ow=0.f;
    #pragma unroll
    for (int ss = 0; ss < 16; ++ss) {
      dsum += red[ss][0][tid];
      ox += red[ss][1][tid]; oy += red[ss][2][tid];
      oz += red[ss][3][tid]; ow += red[ss][4][tid];
    }
    float inv = 1.f / dsum;
    int t = qb*128 + qi_r*4 + j_r;
    int b = g >> 4, u = (g >> 2) & 3, v = g & 3;
    int i = t >> 5, j = t & 31;
    float* ap = att + b*4*16384 + (i*4+u)*128 + (j*4+v);
    ap[0]     = ox*inv;
    ap[16384] = oy*inv;
    ap[32768] = oz*inv;
    ap[49152] = ow*inv;
  }
}

// ================= K4: y = x + (wc@w2)@att + bias (to d_out); h1 = relu(wf1@y) =======
// 256 blocks x 512 threads: 32 quads x 16 groups (4 y-ch + 1 h1-ch each).
__global__ __launch_bounds__(512) void k4_y_h1(
    const float* __restrict__ x, const float* __restrict__ att,
    const float* __restrict__ w2p, const float* __restrict__ b2p,
    const float* __restrict__ wcp, const float* __restrict__ bcp,
    const float* __restrict__ wf1, const float* __restrict__ bf1,
    float* __restrict__ yout, float* __restrict__ h1) {
  __shared__ float sWf[64][4];
  __shared__ float sbf[64];
  __shared__ float sw1[1024];
  __shared__ float sb1[16];
  __shared__ float4 satt[4][32];
  __shared__ float4 ylds[64][32];
  int tid = threadIdx.x;
  if (tid < 256) {
    int o = tid >> 2, k = tid & 3;
    float s = 0.f;
    for (int c = 0; c < 64; ++c) s += wcp[o*64+c] * w2p[c*4+k];
    sWf[o][k] = s;
  }
  if (tid < 64) {
    float s = bcp[tid];
    for (int c = 0; c < 64; ++c) s += wcp[tid*64+c] * b2p[c];
    sbf[tid] = s;
  }
  for (int i = tid; i < 1024; i += 512) sw1[i] = wf1[i];
  if (tid < 16) sb1[tid] = bf1[tid];
  int quad = tid & 31, og = tid >> 5;   // og in [0,16)
  int gq = blockIdx.x*32 + quad;
  int bb = gq >> 12; int px0 = (gq & 4095)*4;
  if (tid < 128) {
    int k = tid >> 5, q2 = tid & 31;
    int gq2 = blockIdx.x*32 + q2;
    int b2i = gq2 >> 12; int p0 = (gq2 & 4095)*4;
    satt[k][q2] = *(const float4*)(att + b2i*4*16384 + k*16384 + p0);
  }
  __syncthreads();
  float4 a0 = satt[0][quad], a1 = satt[1][quad], a2 = satt[2][quad], a3 = satt[3][quad];
  const float* xp = x + bb*CHW + px0;
  float* yp = yout + bb*CHW + px0;
  #pragma unroll
  for (int cc = 0; cc < 4; ++cc) {
    int c = og*4 + cc;
    float4 xv = *(const float4*)(xp + c*16384);
    float w0 = sWf[c][0], w1 = sWf[c][1], w2v = sWf[c][2], w3 = sWf[c][3];
    float bv = sbf[c];
    float4 yv;
    yv.x = xv.x + w0*a0.x + w1*a1.x + w2v*a2.x + w3*a3.x + bv;
    yv.y = xv.y + w0*a0.y + w1*a1.y + w2v*a2.y + w3*a3.y + bv;
    yv.z = xv.z + w0*a0.z + w1*a1.z + w2v*a2.z + w3*a3.z + bv;
    yv.w = xv.w + w0*a0.w + w1*a1.w + w2v*a2.w + w3*a3.w + bv;
    *(float4*)(yp + c*16384) = yv;
    ylds[c][quad] = yv;
  }
  __syncthreads();
  float bv = sb1[og];
  float4 acc = make_float4(bv, bv, bv, bv);
  #pragma unroll 8
  for (int c = 0; c < 64; ++c) {
    float4 yv = ylds[c][quad];
    float wa = sw1[og*64+c];
    acc.x += wa*yv.x; acc.y += wa*yv.y; acc.z += wa*yv.z; acc.w += wa*yv.w;
  }
  acc.x = fmaxf(acc.x,0.f); acc.y = fmaxf(acc.y,0.f);
  acc.z = fmaxf(acc.z,0.f); acc.w = fmaxf(acc.w,0.f);
  *(float4*)(h1 + bb*16*16384 + og*16384 + px0) = acc;
}

// ================= K6: out = y + wf3@relu(dilconv(h1)+bf2) + bf3 =====================
// 256 blocks (one output row each) x 512 threads: 128 px x 4 wave-uniform o2-groups.
__global__ __launch_bounds__(512) void k6_ff_out(
    const float* __restrict__ h1, const float* __restrict__ wf2,
    const float* __restrict__ bf2, const float* __restrict__ wf3,
    const float* __restrict__ bf3, float* yo) {
  __shared__ float sbuf[16][3][136];   // data at col+4; zero pads both sides
  __shared__ float h2buf[128][21];     // stride 21 coprime with 32 banks
  int tid = threadIdx.x;
  int bb = blockIdx.x >> 7, h = blockIdx.x & 127;
  for (int idx = tid; idx < 16*3*136; idx += 512) {
    int c = idx / (3*136);
    int r = (idx / 136) % 3;
    int col = idx % 136;
    int row = h - 5 + 2*r;
    int w = col - 4;
    float v = 0.f;
    if (row >= 0 && w >= 0 && w < 128)
      v = h1[bb*16*16384 + c*16384 + row*128 + w];
    sbuf[c][r][col] = v;
  }
  __syncthreads();
  int w = tid & 127;
  int g = __builtin_amdgcn_readfirstlane(tid >> 7);   // wave-uniform group in [0,4)
  float acc[4];
  #pragma unroll
  for (int o = 0; o < 4; ++o) acc[o] = bf2[g*4+o];
  #pragma unroll 4
  for (int c = 0; c < 16; ++c) {
    #pragma unroll
    for (int r = 0; r < 3; ++r) {
      float tm2 = sbuf[c][r][w+2];
      float t00 = sbuf[c][r][w+4];
      float tp2 = sbuf[c][r][w+6];
      #pragma unroll
      for (int o = 0; o < 4; ++o) {
        const float* wp = wf2 + (((g*4+o)*16 + c)*3 + r)*3;
        acc[o] += wp[0]*tm2 + wp[1]*t00 + wp[2]*tp2;
      }
    }
  }
  #pragma unroll
  for (int o = 0; o < 4; ++o) h2buf[w][g*4+o] = fmaxf(acc[o], 0.f);
  __syncthreads();
  float hv[16];
  #pragma unroll
  for (int k = 0; k < 16; ++k) hv[k] = h2buf[w][k];
  float* ybase = yo + bb*CHW + h*128 + w;
  #pragma unroll 4
  for (int oc = 0; oc < 16; ++oc) {
    int o = g*16 + oc;
    float sv = bf3[o] + ybase[o*16384];
    #pragma unroll
    for (int k = 0; k < 16; ++k) sv += wf3[o*16+k]*hv[k];
    ybase[o*16384] = sv;
  }
}

extern "C" void kernel_launch(void* const* d_in, const int* in_sizes, int n_in,
                              void* d_out, int out_size, void* d_ws, size_t ws_size,
                              hipStream_t stream) {
  (void)in_sizes; (void)n_in; (void)out_size; (void)ws_size;
  const float* x   = (const float*)d_in[0];
  const float* w1a = (const float*)d_in[1];
  const float* b1a = (const float*)d_in[2];
  const float* w1b = (const float*)d_in[3];
  const float* b1b = (const float*)d_in[4];
  const float* wqk = (const float*)d_in[5];
  const float* w2  = (const float*)d_in[6];
  const float* b2  = (const float*)d_in[7];
  const float* wc  = (const float*)d_in[8];
  const float* bc  = (const float*)d_in[9];
  const float* wf1 = (const float*)d_in[10];
  const float* bf1 = (const float*)d_in[11];
  const float* wf2 = (const float*)d_in[12];
  const float* bf2 = (const float*)d_in[13];
  const float* wf3 = (const float*)d_in[14];
  const float* bf3 = (const float*)d_in[15];

  float* ws = (float*)d_ws;
  float*  a_    = ws;                          // 131072 floats
  float*  stats = ws + 131072;                 // 1024
  float4* tok   = (float4*)(ws + 132096);      // 196608 floats
  float4* qkb   = (float4*)(ws + 328704);      // 196608 floats
  float*  att   = ws + 525312;                 // 131072
  float*  h1    = ws + 656384;                 // 524288
  float*  y     = (float*)d_out;               // y staged in d_out; K6 finalizes in place

  k1_a_stats<<<512, 256, 0, stream>>>(x, w1a, b1a, w1b, b1b, a_, stats);
  k2_tok_qk <<<192, 256, 0, stream>>>(a_, stats, wqk, tok, qkb);
  k3_attn   <<<256, 512, 0, stream>>>(tok, qkb, att);
  k4_y_h1   <<<256, 512, 0, stream>>>(x, att, w2, b2, wc, bc, wf1, bf1, y, h1);
  k6_ff_out <<<256, 512, 0, stream>>>(h1, wf2, bf2, wf3, bf3, y);
}